// Round 6
// baseline (621.126 us; speedup 1.0000x reference)
//
#include <hip/hip_runtime.h>
#include <cstdint>

// GIN: N=50000, D=128, E=800000, L=3.
// per layer: agg = x + gather-sum over CSR(dst); x' = relu(relu(agg@W1+b1)@W2+b2)
// CSR built once per launch. Feature math f16 (fp32 accum), MFMA GEMMs, fused MLP.
// - bucket scatter: XCC-pinned (s_getreg HW_REG_XCC_ID) + ticket work-stealing
//   so each partition's ssrc/pos window stays in its own XCD's L2.
// - gather processed in degree-sorted order (counting sort) for wave uniformity.

constexpr int N = 50000;
constexpr int D = 128;
constexpr int E = 800000;
constexpr int L = 3;
constexpr int NB_SCAN = (N + 255) / 256;  // 196
constexpr int PART = 8;
constexpr int NPN = N / PART;             // 6250
constexpr int STRIPES = 128;              // per partition
constexpr int SSIZE = E / STRIPES;        // 6250 edges per stripe (exact)
constexpr int WROW = 136;                 // padded LDS row (f16)

typedef _Float16 f16;
typedef _Float16 f16x8 __attribute__((ext_vector_type(8)));
typedef float f32x4 __attribute__((ext_vector_type(4)));

// ---- edge index load (handles int32 or int64 storage) ----
__device__ __forceinline__ bool ei_is64(const int* ei) {
  return (ei[1] == 0) && (ei[3] == 0) && (ei[5] == 0);
}
__device__ __forceinline__ int ei_src(const int* ei, int e, bool is64) {
  return is64 ? ei[2 * (size_t)e] : ei[e];
}
__device__ __forceinline__ int ei_dst(const int* ei, int e, bool is64) {
  return is64 ? ei[2 * ((size_t)E + e)] : ei[(size_t)E + e];
}

// ---------------- merged one-time prep: wprep + cvt + edge convert/hist ----
// grid = 384 + 3125 + 3125 = 6634 blocks, every segment exact.
__global__ __launch_bounds__(256) void k_init(const float* __restrict__ x0,
                                              const int* __restrict__ ei,
                                              const float* __restrict__ W1,
                                              const float* __restrict__ W2,
                                              f16* __restrict__ Wt,
                                              f16* __restrict__ xh,
                                              int* __restrict__ src32,
                                              int* __restrict__ dst32,
                                              int* __restrict__ cnt) {
  const int bid = blockIdx.x;
  if (bid < 384) {
    // Wt[m][c][k] = Wsrc[m][k][c] as f16 (first L from W1, rest W2)
    int i = bid * 256 + threadIdx.x;
    int m = i >> 14;
    int c = (i >> 7) & 127;
    int k = i & 127;
    const float* src = (m < L) ? (W1 + (size_t)m * D * D)
                               : (W2 + (size_t)(m - L) * D * D);
    Wt[i] = (f16)src[(size_t)k * D + c];
  } else if (bid < 384 + 3125) {
    // x0 f32 -> xh f16, 8 elems/thread
    int i = (bid - 384) * 256 + threadIdx.x;
    float4 v0 = *(const float4*)(x0 + (size_t)i * 8);
    float4 v1 = *(const float4*)(x0 + (size_t)i * 8 + 4);
    f16x8 o = {(f16)v0.x, (f16)v0.y, (f16)v0.z, (f16)v0.w,
               (f16)v1.x, (f16)v1.y, (f16)v1.z, (f16)v1.w};
    *(f16x8*)(xh + (size_t)i * 8) = o;
  } else {
    // edge index -> int32 arrays + dst histogram
    int e = (bid - (384 + 3125)) * 256 + threadIdx.x;
    bool is64 = ei_is64(ei);
    int s = ei_src(ei, e, is64);
    int t = ei_dst(ei, e, is64);
    src32[e] = s;
    dst32[e] = t;
    atomicAdd(cnt + t, 1);
  }
}

// ---------------- scans ----------------
__global__ __launch_bounds__(256) void k_scan1(const int* __restrict__ cnt,
                                               int* __restrict__ off,
                                               int* __restrict__ bsum) {
  __shared__ int s[256];
  int i = blockIdx.x * 256 + threadIdx.x;
  int v = (i < N) ? cnt[i] : 0;
  s[threadIdx.x] = v;
  __syncthreads();
#pragma unroll
  for (int o = 1; o < 256; o <<= 1) {
    int t = (threadIdx.x >= o) ? s[threadIdx.x - o] : 0;
    __syncthreads();
    s[threadIdx.x] += t;
    __syncthreads();
  }
  if (i < N) off[i] = s[threadIdx.x] - v;
  if (threadIdx.x == 255) bsum[blockIdx.x] = s[255];
}

// also zeroes degree bins + tickets (runs before dhist/bucket)
__global__ __launch_bounds__(256) void k_scan2(int* __restrict__ bsum,
                                               int* __restrict__ dbin,
                                               int* __restrict__ tick) {
  __shared__ int s[256];
  int v = (threadIdx.x < NB_SCAN) ? bsum[threadIdx.x] : 0;
  s[threadIdx.x] = v;
  __syncthreads();
#pragma unroll
  for (int o = 1; o < 256; o <<= 1) {
    int t = (threadIdx.x >= o) ? s[threadIdx.x - o] : 0;
    __syncthreads();
    s[threadIdx.x] += t;
    __syncthreads();
  }
  if (threadIdx.x < NB_SCAN) bsum[threadIdx.x] = s[threadIdx.x] - v;
  if (threadIdx.x < 64) dbin[threadIdx.x] = 0;
  if (threadIdx.x < PART) tick[threadIdx.x] = 0;
}

__global__ __launch_bounds__(256) void k_scan3(int* __restrict__ off,
                                               const int* __restrict__ bsum,
                                               int* __restrict__ pos) {
  int i = blockIdx.x * 256 + threadIdx.x;
  if (i < N) {
    int o = off[i] + bsum[i >> 8];
    off[i] = o;
    pos[i] = o;
  }
  if (i == 0) off[N] = E;
}

// ---------------- degree counting-sort (node perm for gather balance) -----
__global__ __launch_bounds__(256) void k_dhist(const int* __restrict__ off,
                                               int* __restrict__ dbin) {
  int i = blockIdx.x * 256 + threadIdx.x;
  if (i < N) {
    int deg = off[i + 1] - off[i];
    atomicAdd(dbin + min(deg, 63), 1);
  }
}

__global__ __launch_bounds__(64) void k_dscan(const int* __restrict__ dbin,
                                              int* __restrict__ dcur) {
  __shared__ int s[64];
  int t = threadIdx.x;
  s[t] = dbin[t];
  __syncthreads();
  if (t == 0) {
    int r = 0;
#pragma unroll
    for (int i = 0; i < 64; ++i) {
      int v = s[i];
      s[i] = r;
      r += v;
    }
  }
  __syncthreads();
  dcur[t] = s[t];
}

__global__ __launch_bounds__(256) void k_dscatter(const int* __restrict__ off,
                                                  int* __restrict__ dcur,
                                                  int* __restrict__ perm) {
  int i = blockIdx.x * 256 + threadIdx.x;
  if (i < N) {
    int deg = off[i + 1] - off[i];
    int p = atomicAdd(dcur + min(deg, 63), 1);
    perm[p] = i;
  }
}

// ---------------- bucket scatter: XCC-pinned + work stealing ----------------
// partition q's pos window (25KB) and ssrc window (~400KB) are touched only by
// blocks physically on XCD q (ticket stealing keeps correctness if the XCC
// read is ever wrong/garbage).
__global__ __launch_bounds__(256) void k_bucket_steal(const int* __restrict__ src32,
                                                      const int* __restrict__ dst32,
                                                      int* __restrict__ pos,
                                                      int* __restrict__ ssrc,
                                                      int* __restrict__ tick) {
  __shared__ int s_t;
  // hwreg(HW_REG_XCC_ID=20, offset=0, size=4) -> (4-1)<<11 | 0<<6 | 20 = 6164
  const int my = (int)(__builtin_amdgcn_s_getreg(6164)) & (PART - 1);
  for (int q8 = 0; q8 < PART; ++q8) {
    const int q = (my + q8) & (PART - 1);
    const int lo = q * NPN;
    while (true) {
      __syncthreads();
      if (threadIdx.x == 0) s_t = atomicAdd(tick + q, 1);
      __syncthreads();
      const int t = s_t;
      if (t >= STRIPES) break;
      const int e_end = (t + 1) * SSIZE;
      for (int e = t * SSIZE + threadIdx.x; e < e_end; e += 256) {
        int d = dst32[e];
        if ((unsigned)(d - lo) < (unsigned)NPN) {
          int p = atomicAdd(pos + d, 1);
          ssrc[p] = src32[e];
        }
      }
    }
  }
}

// ---------------- gather-aggregate (f16), degree-sorted order ----------------
// 16 nodes/block x 16 lanes; lane owns 8 dims (16B); 4-way unrolled MLP.
__global__ __launch_bounds__(256) void k_gather_f16(const f16* __restrict__ x,
                                                    const int* __restrict__ off,
                                                    const int* __restrict__ ssrc,
                                                    const int* __restrict__ perm,
                                                    f16* __restrict__ agg) {
  int slot = blockIdx.x * 16 + (threadIdx.x >> 4);
  int n = perm[slot];
  const int d0 = (threadIdx.x & 15) << 3;
  f16x8 v = *(const f16x8*)(x + (size_t)n * D + d0);
  float acc[8];
#pragma unroll
  for (int j = 0; j < 8; ++j) acc[j] = (float)v[j];
  const int beg = off[n], end = off[n + 1];
  int p = beg;
  for (; p + 4 <= end; p += 4) {
    int s0 = ssrc[p];
    int s1 = ssrc[p + 1];
    int s2 = ssrc[p + 2];
    int s3 = ssrc[p + 3];
    f16x8 u0 = *(const f16x8*)(x + (size_t)s0 * D + d0);
    f16x8 u1 = *(const f16x8*)(x + (size_t)s1 * D + d0);
    f16x8 u2 = *(const f16x8*)(x + (size_t)s2 * D + d0);
    f16x8 u3 = *(const f16x8*)(x + (size_t)s3 * D + d0);
#pragma unroll
    for (int j = 0; j < 8; ++j)
      acc[j] += (float)u0[j] + (float)u1[j] + (float)u2[j] + (float)u3[j];
  }
  for (; p < end; ++p) {
    int s = ssrc[p];
    f16x8 u = *(const f16x8*)(x + (size_t)s * D + d0);
#pragma unroll
    for (int j = 0; j < 8; ++j) acc[j] += (float)u[j];
  }
  f16x8 o;
#pragma unroll
  for (int j = 0; j < 8; ++j) o[j] = (f16)acc[j];
  *(f16x8*)(agg + (size_t)n * D + d0) = o;
}

// ---------------- fused double MFMA GEMM + bias + ReLU ----------------
// x' = relu(relu(A@W1+b1)@W2+b2). A f16 row-major; Wt* f16 [col][k].
// Block: 256 thr = 4 waves, 64 rows. h (64x128 f16) never leaves LDS.
__global__ __launch_bounds__(256) void k_gemm_fused(const f16* __restrict__ A,
                                                    const f16* __restrict__ Wt1,
                                                    const f16* __restrict__ Wt2,
                                                    const float* __restrict__ b1,
                                                    const float* __restrict__ b2,
                                                    f16* __restrict__ Ch,
                                                    float* __restrict__ Cf) {
  __shared__ f16 Ws[2][128 * WROW];
  {
    const f16x8* g1 = (const f16x8*)Wt1;
    const f16x8* g2 = (const f16x8*)Wt2;
    for (int i = threadIdx.x; i < 2048; i += 256) {
      int c = i >> 4;
      int k8 = (i & 15) << 3;
      *(f16x8*)&Ws[0][c * WROW + k8] = g1[i];
      *(f16x8*)&Ws[1][c * WROW + k8] = g2[i];
    }
  }
  __syncthreads();

  const int w = threadIdx.x >> 6;
  const int l = threadIdx.x & 63;
  const int l15 = l & 15;
  const int g = l >> 4;
  const int r0 = blockIdx.x * 64 + w * 16;

  // ---- phase A: h = relu(A @ W1 + b1) ----
  const int arow = min(r0 + l15, N - 1);
  const f16* Arow = A + (size_t)arow * D;
  f16x8 a[4];
#pragma unroll
  for (int t = 0; t < 4; ++t)
    a[t] = *(const f16x8*)(Arow + t * 32 + g * 8);

  float bc1[8], bc2[8];
#pragma unroll
  for (int c = 0; c < 8; ++c) {
    bc1[c] = b1[c * 16 + l15];
    bc2[c] = b2[c * 16 + l15];
  }

  f32x4 acc[8];
#pragma unroll
  for (int c = 0; c < 8; ++c) acc[c] = (f32x4){0.f, 0.f, 0.f, 0.f};
#pragma unroll
  for (int t = 0; t < 4; ++t) {
#pragma unroll
    for (int c = 0; c < 8; ++c) {
      f16x8 b = *(const f16x8*)&Ws[0][(c * 16 + l15) * WROW + t * 32 + g * 8];
      acc[c] = __builtin_amdgcn_mfma_f32_16x16x32_f16(a[t], b, acc[c], 0, 0, 0);
    }
  }

  __syncthreads();  // all waves done reading Ws[0]

  f16* hbuf = &Ws[0][0];
#pragma unroll
  for (int r = 0; r < 4; ++r) {
    int hr = w * 16 + g * 4 + r;
#pragma unroll
    for (int c = 0; c < 8; ++c) {
      float vv = fmaxf(acc[c][r] + bc1[c], 0.0f);
      hbuf[hr * WROW + c * 16 + l15] = (f16)vv;
    }
  }
  __syncthreads();

  // ---- phase B: x' = relu(h @ W2 + b2) ----
  f16x8 a2[4];
#pragma unroll
  for (int t = 0; t < 4; ++t)
    a2[t] = *(const f16x8*)&hbuf[(w * 16 + l15) * WROW + t * 32 + g * 8];

#pragma unroll
  for (int c = 0; c < 8; ++c) acc[c] = (f32x4){0.f, 0.f, 0.f, 0.f};
#pragma unroll
  for (int t = 0; t < 4; ++t) {
#pragma unroll
    for (int c = 0; c < 8; ++c) {
      f16x8 b = *(const f16x8*)&Ws[1][(c * 16 + l15) * WROW + t * 32 + g * 8];
      acc[c] = __builtin_amdgcn_mfma_f32_16x16x32_f16(a2[t], b, acc[c], 0, 0, 0);
    }
  }

#pragma unroll
  for (int r = 0; r < 4; ++r) {
    int rr = r0 + g * 4 + r;
    if (rr < N) {
#pragma unroll
      for (int c = 0; c < 8; ++c) {
        int col = c * 16 + l15;
        float vv = fmaxf(acc[c][r] + bc2[c], 0.0f);
        Ch[(size_t)rr * D + col] = (f16)vv;
        if (Cf) Cf[(size_t)rr * D + col] = vv;
      }
    }
  }
}

extern "C" void kernel_launch(void* const* d_in, const int* in_sizes, int n_in,
                              void* d_out, int out_size, void* d_ws, size_t ws_size,
                              hipStream_t stream) {
  const float* x0 = (const float*)d_in[0];
  const int* ei   = (const int*)d_in[1];
  const float* W1 = (const float*)d_in[2];
  const float* b1 = (const float*)d_in[3];
  const float* W2 = (const float*)d_in[4];
  const float* b2 = (const float*)d_in[5];
  float* out = (float*)d_out;

  // workspace layout
  f16* xh    = (f16*)d_ws;                          // N*D
  f16* aggh  = xh + (size_t)N * D;                  // N*D
  f16* Wt    = aggh + (size_t)N * D;                // 2*L*D*D
  int* off   = (int*)(Wt + (size_t)2 * L * D * D);  // N+1
  int* pos   = off + (N + 1);                       // N (also cnt)
  int* bsum  = pos + N;                             // 256
  int* dbin  = bsum + 256;                          // 64
  int* dcur  = dbin + 64;                           // 64
  int* tick  = dcur + 64;                           // 64 (8 used)
  int* perm  = tick + 64;                           // N
  int* ssrc  = perm + N;                            // E
  int* src32 = ssrc + E;                            // E
  int* dst32 = src32 + E;                           // E

  const dim3 blk(256);

  // ---- one-time prep ----
  hipMemsetAsync(pos, 0, (size_t)N * sizeof(int), stream);
  k_init<<<384 + 3125 + 3125, blk, 0, stream>>>(x0, ei, W1, W2, Wt, xh, src32,
                                                dst32, pos);
  k_scan1<<<NB_SCAN, blk, 0, stream>>>(pos, off, bsum);
  k_scan2<<<1, blk, 0, stream>>>(bsum, dbin, tick);
  k_scan3<<<NB_SCAN, blk, 0, stream>>>(off, bsum, pos);
  k_dhist<<<NB_SCAN, blk, 0, stream>>>(off, dbin);
  k_dscan<<<1, dim3(64), 0, stream>>>(dbin, dcur);
  k_dscatter<<<NB_SCAN, blk, 0, stream>>>(off, dcur, perm);
  k_bucket_steal<<<1024, blk, 0, stream>>>(src32, dst32, pos, ssrc, tick);

  const int gemm_blocks = (N + 63) / 64;  // 782
  const int gather_blocks = N / 16;       // 3125

  for (int l = 0; l < L; ++l) {
    k_gather_f16<<<gather_blocks, blk, 0, stream>>>(xh, off, ssrc, perm, aggh);
    k_gemm_fused<<<gemm_blocks, blk, 0, stream>>>(
        aggh, Wt + (size_t)l * D * D, Wt + (size_t)(L + l) * D * D,
        b1 + (size_t)l * D, b2 + (size_t)l * D, xh,
        (l == L - 1) ? out : nullptr);
  }
}

// Round 7
// 326.630 us; speedup vs baseline: 1.9016x; 1.9016x over previous
//
#include <hip/hip_runtime.h>
#include <cstdint>

// GIN: N=50000, D=128, E=800000, L=3.
// per layer: agg = x + gather-sum over CSR(dst); x' = relu(relu(agg@W1+b1)@W2+b2)
// CSR built once per launch. Feature math f16 (fp32 accum), MFMA GEMMs, fused MLP.
// - k_init's dst-histogram atomicAdd RETURNS each edge's rank -> bucket pass is
//   atomic-free (plain write to ssrc[off[d]+rank[e]]).
// - bucket XCC-pinned (s_getreg HW_REG_XCC_ID) + ticket stealing: each dst-range
//   partition's ssrc window (~400KB) goes dirty in exactly one XCD's L2.
// - gather: 16 lanes/node, 3125 blocks, 8-way unrolled neighbor loop (MLP).

constexpr int N = 50000;
constexpr int D = 128;
constexpr int E = 800000;
constexpr int L = 3;
constexpr int NB_SCAN = (N + 255) / 256;  // 196
constexpr int PART = 8;
constexpr int NPN = N / PART;             // 6250
constexpr int STRIPES = 128;              // per partition
constexpr int SSIZE = E / STRIPES;        // 6250 edges per stripe (exact)
constexpr int WROW = 136;                 // padded LDS row (f16)

typedef _Float16 f16;
typedef _Float16 f16x8 __attribute__((ext_vector_type(8)));
typedef float f32x4 __attribute__((ext_vector_type(4)));

// ---- edge index load (handles int32 or int64 storage) ----
__device__ __forceinline__ bool ei_is64(const int* ei) {
  return (ei[1] == 0) && (ei[3] == 0) && (ei[5] == 0);
}
__device__ __forceinline__ int ei_src(const int* ei, int e, bool is64) {
  return is64 ? ei[2 * (size_t)e] : ei[e];
}
__device__ __forceinline__ int ei_dst(const int* ei, int e, bool is64) {
  return is64 ? ei[2 * ((size_t)E + e)] : ei[(size_t)E + e];
}

// ---------------- merged one-time prep: wprep + cvt + edge convert/hist/rank --
// grid = 384 + 3125 + 3125 = 6634 blocks, every segment exact.
__global__ __launch_bounds__(256) void k_init(const float* __restrict__ x0,
                                              const int* __restrict__ ei,
                                              const float* __restrict__ W1,
                                              const float* __restrict__ W2,
                                              f16* __restrict__ Wt,
                                              f16* __restrict__ xh,
                                              int* __restrict__ src32,
                                              int* __restrict__ dst32,
                                              int* __restrict__ rank,
                                              int* __restrict__ cnt) {
  const int bid = blockIdx.x;
  if (bid < 384) {
    // Wt[m][c][k] = Wsrc[m][k][c] as f16 (first L from W1, rest W2)
    int i = bid * 256 + threadIdx.x;
    int m = i >> 14;
    int c = (i >> 7) & 127;
    int k = i & 127;
    const float* src = (m < L) ? (W1 + (size_t)m * D * D)
                               : (W2 + (size_t)(m - L) * D * D);
    Wt[i] = (f16)src[(size_t)k * D + c];
  } else if (bid < 384 + 3125) {
    // x0 f32 -> xh f16, 8 elems/thread
    int i = (bid - 384) * 256 + threadIdx.x;
    float4 v0 = *(const float4*)(x0 + (size_t)i * 8);
    float4 v1 = *(const float4*)(x0 + (size_t)i * 8 + 4);
    f16x8 o = {(f16)v0.x, (f16)v0.y, (f16)v0.z, (f16)v0.w,
               (f16)v1.x, (f16)v1.y, (f16)v1.z, (f16)v1.w};
    *(f16x8*)(xh + (size_t)i * 8) = o;
  } else {
    // edge index -> int32 arrays + dst histogram; returned old count = rank
    int e = (bid - (384 + 3125)) * 256 + threadIdx.x;
    bool is64 = ei_is64(ei);
    int s = ei_src(ei, e, is64);
    int t = ei_dst(ei, e, is64);
    src32[e] = s;
    dst32[e] = t;
    rank[e] = atomicAdd(cnt + t, 1);
  }
}

// ---------------- scans ----------------
__global__ __launch_bounds__(256) void k_scan1(const int* __restrict__ cnt,
                                               int* __restrict__ off,
                                               int* __restrict__ bsum) {
  __shared__ int s[256];
  int i = blockIdx.x * 256 + threadIdx.x;
  int v = (i < N) ? cnt[i] : 0;
  s[threadIdx.x] = v;
  __syncthreads();
#pragma unroll
  for (int o = 1; o < 256; o <<= 1) {
    int t = (threadIdx.x >= o) ? s[threadIdx.x - o] : 0;
    __syncthreads();
    s[threadIdx.x] += t;
    __syncthreads();
  }
  if (i < N) off[i] = s[threadIdx.x] - v;
  if (threadIdx.x == 255) bsum[blockIdx.x] = s[255];
}

// also zeroes bucket tickets
__global__ __launch_bounds__(256) void k_scan2(int* __restrict__ bsum,
                                               int* __restrict__ tick) {
  __shared__ int s[256];
  int v = (threadIdx.x < NB_SCAN) ? bsum[threadIdx.x] : 0;
  s[threadIdx.x] = v;
  __syncthreads();
#pragma unroll
  for (int o = 1; o < 256; o <<= 1) {
    int t = (threadIdx.x >= o) ? s[threadIdx.x - o] : 0;
    __syncthreads();
    s[threadIdx.x] += t;
    __syncthreads();
  }
  if (threadIdx.x < NB_SCAN) bsum[threadIdx.x] = s[threadIdx.x] - v;
  if (threadIdx.x < PART) tick[threadIdx.x] = 0;
}

__global__ __launch_bounds__(256) void k_scan3(int* __restrict__ off,
                                               const int* __restrict__ bsum) {
  int i = blockIdx.x * 256 + threadIdx.x;
  if (i < N) off[i] += bsum[i >> 8];
  if (i == 0) off[N] = E;
}

// ---------------- bucket scatter: atomic-free, XCC-pinned + stealing --------
// ssrc[off[d] + rank[e]] = src32[e]; partition q (dst in [q*NPN,(q+1)*NPN)) is
// processed by blocks physically on XCD q (ticket stealing keeps correctness
// for any XCC mapping). Pure streaming reads + partition-local writes.
__global__ __launch_bounds__(256) void k_bucket_steal(const int* __restrict__ src32,
                                                      const int* __restrict__ dst32,
                                                      const int* __restrict__ rank,
                                                      const int* __restrict__ off,
                                                      int* __restrict__ ssrc,
                                                      int* __restrict__ tick) {
  __shared__ int s_t;
  // hwreg(HW_REG_XCC_ID=20, offset=0, size=4) -> (4-1)<<11 | 20 = 6164
  const int my = (int)(__builtin_amdgcn_s_getreg(6164)) & (PART - 1);
  for (int q8 = 0; q8 < PART; ++q8) {
    const int q = (my + q8) & (PART - 1);
    const int lo = q * NPN;
    while (true) {
      __syncthreads();
      if (threadIdx.x == 0) s_t = atomicAdd(tick + q, 1);
      __syncthreads();
      const int t = s_t;
      if (t >= STRIPES) break;
      const int e_end = (t + 1) * SSIZE;
      for (int e = t * SSIZE + threadIdx.x; e < e_end; e += 256) {
        int d = dst32[e];
        if ((unsigned)(d - lo) < (unsigned)NPN)
          ssrc[off[d] + rank[e]] = src32[e];
      }
    }
  }
}

// ---------------- gather-aggregate (f16): agg[n] = x[n] + sum_{j} x[src_j]
// 16 nodes/block x 16 lanes; lane owns 8 dims (16B); 8-way unrolled MLP.
__global__ __launch_bounds__(256) void k_gather_f16(const f16* __restrict__ x,
                                                    const int* __restrict__ off,
                                                    const int* __restrict__ ssrc,
                                                    f16* __restrict__ agg) {
  int n = blockIdx.x * 16 + (threadIdx.x >> 4);
  if (n >= N) return;
  const int d0 = (threadIdx.x & 15) << 3;
  f16x8 v = *(const f16x8*)(x + (size_t)n * D + d0);
  float acc[8];
#pragma unroll
  for (int j = 0; j < 8; ++j) acc[j] = (float)v[j];
  const int beg = off[n], end = off[n + 1];
  int p = beg;
  for (; p + 8 <= end; p += 8) {
    f16x8 u[8];
#pragma unroll
    for (int q = 0; q < 8; ++q) {
      int s = ssrc[p + q];
      u[q] = *(const f16x8*)(x + (size_t)s * D + d0);
    }
#pragma unroll
    for (int q = 0; q < 8; ++q)
#pragma unroll
      for (int j = 0; j < 8; ++j) acc[j] += (float)u[q][j];
  }
  if (p + 4 <= end) {
    f16x8 u[4];
#pragma unroll
    for (int q = 0; q < 4; ++q) {
      int s = ssrc[p + q];
      u[q] = *(const f16x8*)(x + (size_t)s * D + d0);
    }
#pragma unroll
    for (int q = 0; q < 4; ++q)
#pragma unroll
      for (int j = 0; j < 8; ++j) acc[j] += (float)u[q][j];
    p += 4;
  }
  for (; p < end; ++p) {
    int s = ssrc[p];
    f16x8 u = *(const f16x8*)(x + (size_t)s * D + d0);
#pragma unroll
    for (int j = 0; j < 8; ++j) acc[j] += (float)u[j];
  }
  f16x8 o;
#pragma unroll
  for (int j = 0; j < 8; ++j) o[j] = (f16)acc[j];
  *(f16x8*)(agg + (size_t)n * D + d0) = o;
}

// ---------------- fused double MFMA GEMM + bias + ReLU ----------------
// x' = relu(relu(A@W1+b1)@W2+b2). A f16 row-major; Wt* f16 [col][k].
// Block: 256 thr = 4 waves, 64 rows. h (64x128 f16) never leaves LDS.
__global__ __launch_bounds__(256) void k_gemm_fused(const f16* __restrict__ A,
                                                    const f16* __restrict__ Wt1,
                                                    const f16* __restrict__ Wt2,
                                                    const float* __restrict__ b1,
                                                    const float* __restrict__ b2,
                                                    f16* __restrict__ Ch,
                                                    float* __restrict__ Cf) {
  __shared__ f16 Ws[2][128 * WROW];
  {
    const f16x8* g1 = (const f16x8*)Wt1;
    const f16x8* g2 = (const f16x8*)Wt2;
    for (int i = threadIdx.x; i < 2048; i += 256) {
      int c = i >> 4;
      int k8 = (i & 15) << 3;
      *(f16x8*)&Ws[0][c * WROW + k8] = g1[i];
      *(f16x8*)&Ws[1][c * WROW + k8] = g2[i];
    }
  }
  __syncthreads();

  const int w = threadIdx.x >> 6;
  const int l = threadIdx.x & 63;
  const int l15 = l & 15;
  const int g = l >> 4;
  const int r0 = blockIdx.x * 64 + w * 16;

  // ---- phase A: h = relu(A @ W1 + b1) ----
  const int arow = min(r0 + l15, N - 1);
  const f16* Arow = A + (size_t)arow * D;
  f16x8 a[4];
#pragma unroll
  for (int t = 0; t < 4; ++t)
    a[t] = *(const f16x8*)(Arow + t * 32 + g * 8);

  float bc1[8], bc2[8];
#pragma unroll
  for (int c = 0; c < 8; ++c) {
    bc1[c] = b1[c * 16 + l15];
    bc2[c] = b2[c * 16 + l15];
  }

  f32x4 acc[8];
#pragma unroll
  for (int c = 0; c < 8; ++c) acc[c] = (f32x4){0.f, 0.f, 0.f, 0.f};
#pragma unroll
  for (int t = 0; t < 4; ++t) {
#pragma unroll
    for (int c = 0; c < 8; ++c) {
      f16x8 b = *(const f16x8*)&Ws[0][(c * 16 + l15) * WROW + t * 32 + g * 8];
      acc[c] = __builtin_amdgcn_mfma_f32_16x16x32_f16(a[t], b, acc[c], 0, 0, 0);
    }
  }

  __syncthreads();  // all waves done reading Ws[0]

  f16* hbuf = &Ws[0][0];
#pragma unroll
  for (int r = 0; r < 4; ++r) {
    int hr = w * 16 + g * 4 + r;
#pragma unroll
    for (int c = 0; c < 8; ++c) {
      float vv = fmaxf(acc[c][r] + bc1[c], 0.0f);
      hbuf[hr * WROW + c * 16 + l15] = (f16)vv;
    }
  }
  __syncthreads();

  // ---- phase B: x' = relu(h @ W2 + b2) ----
  f16x8 a2[4];
#pragma unroll
  for (int t = 0; t < 4; ++t)
    a2[t] = *(const f16x8*)&hbuf[(w * 16 + l15) * WROW + t * 32 + g * 8];

#pragma unroll
  for (int c = 0; c < 8; ++c) acc[c] = (f32x4){0.f, 0.f, 0.f, 0.f};
#pragma unroll
  for (int t = 0; t < 4; ++t) {
#pragma unroll
    for (int c = 0; c < 8; ++c) {
      f16x8 b = *(const f16x8*)&Ws[1][(c * 16 + l15) * WROW + t * 32 + g * 8];
      acc[c] = __builtin_amdgcn_mfma_f32_16x16x32_f16(a2[t], b, acc[c], 0, 0, 0);
    }
  }

#pragma unroll
  for (int r = 0; r < 4; ++r) {
    int rr = r0 + g * 4 + r;
    if (rr < N) {
#pragma unroll
      for (int c = 0; c < 8; ++c) {
        int col = c * 16 + l15;
        float vv = fmaxf(acc[c][r] + bc2[c], 0.0f);
        Ch[(size_t)rr * D + col] = (f16)vv;
        if (Cf) Cf[(size_t)rr * D + col] = vv;
      }
    }
  }
}

extern "C" void kernel_launch(void* const* d_in, const int* in_sizes, int n_in,
                              void* d_out, int out_size, void* d_ws, size_t ws_size,
                              hipStream_t stream) {
  const float* x0 = (const float*)d_in[0];
  const int* ei   = (const int*)d_in[1];
  const float* W1 = (const float*)d_in[2];
  const float* b1 = (const float*)d_in[3];
  const float* W2 = (const float*)d_in[4];
  const float* b2 = (const float*)d_in[5];
  float* out = (float*)d_out;

  // workspace layout
  f16* xh    = (f16*)d_ws;                          // N*D
  f16* aggh  = xh + (size_t)N * D;                  // N*D
  f16* Wt    = aggh + (size_t)N * D;                // 2*L*D*D
  int* off   = (int*)(Wt + (size_t)2 * L * D * D);  // N+1
  int* cnt   = off + (N + 1);                       // N
  int* bsum  = cnt + N;                             // 256
  int* tick  = bsum + 256;                          // 64 (8 used)
  int* ssrc  = tick + 64;                           // E
  int* src32 = ssrc + E;                            // E
  int* dst32 = src32 + E;                           // E
  int* rank  = dst32 + E;                           // E

  const dim3 blk(256);

  // ---- one-time prep ----
  hipMemsetAsync(cnt, 0, (size_t)N * sizeof(int), stream);
  k_init<<<384 + 3125 + 3125, blk, 0, stream>>>(x0, ei, W1, W2, Wt, xh, src32,
                                                dst32, rank, cnt);
  k_scan1<<<NB_SCAN, blk, 0, stream>>>(cnt, off, bsum);
  k_scan2<<<1, blk, 0, stream>>>(bsum, tick);
  k_scan3<<<NB_SCAN, blk, 0, stream>>>(off, bsum);
  k_bucket_steal<<<1024, blk, 0, stream>>>(src32, dst32, rank, off, ssrc, tick);

  const int gemm_blocks = (N + 63) / 64;  // 782
  const int gather_blocks = N / 16;       // 3125

  for (int l = 0; l < L; ++l) {
    k_gather_f16<<<gather_blocks, blk, 0, stream>>>(xh, off, ssrc, aggh);
    k_gemm_fused<<<gemm_blocks, blk, 0, stream>>>(
        aggh, Wt + (size_t)l * D * D, Wt + (size_t)(L + l) * D * D,
        b1 + (size_t)l * D, b2 + (size_t)l * D, xh,
        (l == L - 1) ? out : nullptr);
  }
}

// Round 8
// 217.192 us; speedup vs baseline: 2.8598x; 1.5039x over previous
//
#include <hip/hip_runtime.h>
#include <cstdint>

// GIN: N=50000, D=128, E=800000, L=3.
// per layer: agg = x + gather-sum over CSR(dst); x' = relu(relu(agg@W1+b1)@W2+b2)
// CSR built once per launch. Feature math f16 (fp32 accum), MFMA GEMMs, fused MLP.
// - k_init's dst-histogram atomicAdd RETURNS each edge's rank (packed with src
//   into int2) -> bucket pass is a single flat atomic-free scatter:
//   ssrc[off[d]+rank] = src. Partial-line writebacks merge in L2/L3.
// - gather: 16 lanes/node, 3125 blocks, 8-way unrolled neighbor loop (MLP).

constexpr int N = 50000;
constexpr int D = 128;
constexpr int E = 800000;
constexpr int L = 3;
constexpr int NB_SCAN = (N + 255) / 256;  // 196
constexpr int WROW = 136;                 // padded LDS row (f16)

typedef _Float16 f16;
typedef _Float16 f16x8 __attribute__((ext_vector_type(8)));
typedef float f32x4 __attribute__((ext_vector_type(4)));

// ---- edge index load (handles int32 or int64 storage) ----
__device__ __forceinline__ bool ei_is64(const int* ei) {
  return (ei[1] == 0) && (ei[3] == 0) && (ei[5] == 0);
}
__device__ __forceinline__ int ei_src(const int* ei, int e, bool is64) {
  return is64 ? ei[2 * (size_t)e] : ei[e];
}
__device__ __forceinline__ int ei_dst(const int* ei, int e, bool is64) {
  return is64 ? ei[2 * ((size_t)E + e)] : ei[(size_t)E + e];
}

// ---------------- merged one-time prep: wprep + cvt + edge convert/hist/rank --
// grid = 384 + 3125 + 3125 = 6634 blocks, every segment exact.
__global__ __launch_bounds__(256) void k_init(const float* __restrict__ x0,
                                              const int* __restrict__ ei,
                                              const float* __restrict__ W1,
                                              const float* __restrict__ W2,
                                              f16* __restrict__ Wt,
                                              f16* __restrict__ xh,
                                              int* __restrict__ dst32,
                                              int2* __restrict__ srk,
                                              int* __restrict__ cnt) {
  const int bid = blockIdx.x;
  if (bid < 384) {
    // Wt[m][c][k] = Wsrc[m][k][c] as f16 (first L from W1, rest W2)
    int i = bid * 256 + threadIdx.x;
    int m = i >> 14;
    int c = (i >> 7) & 127;
    int k = i & 127;
    const float* src = (m < L) ? (W1 + (size_t)m * D * D)
                               : (W2 + (size_t)(m - L) * D * D);
    Wt[i] = (f16)src[(size_t)k * D + c];
  } else if (bid < 384 + 3125) {
    // x0 f32 -> xh f16, 8 elems/thread
    int i = (bid - 384) * 256 + threadIdx.x;
    float4 v0 = *(const float4*)(x0 + (size_t)i * 8);
    float4 v1 = *(const float4*)(x0 + (size_t)i * 8 + 4);
    f16x8 o = {(f16)v0.x, (f16)v0.y, (f16)v0.z, (f16)v0.w,
               (f16)v1.x, (f16)v1.y, (f16)v1.z, (f16)v1.w};
    *(f16x8*)(xh + (size_t)i * 8) = o;
  } else {
    // edge index -> int32 arrays + dst histogram; returned old count = rank
    int e = (bid - (384 + 3125)) * 256 + threadIdx.x;
    bool is64 = ei_is64(ei);
    int s = ei_src(ei, e, is64);
    int t = ei_dst(ei, e, is64);
    dst32[e] = t;
    int r = atomicAdd(cnt + t, 1);
    srk[e] = make_int2(s, r);
  }
}

// ---------------- scans ----------------
__global__ __launch_bounds__(256) void k_scan1(const int* __restrict__ cnt,
                                               int* __restrict__ off,
                                               int* __restrict__ bsum) {
  __shared__ int s[256];
  int i = blockIdx.x * 256 + threadIdx.x;
  int v = (i < N) ? cnt[i] : 0;
  s[threadIdx.x] = v;
  __syncthreads();
#pragma unroll
  for (int o = 1; o < 256; o <<= 1) {
    int t = (threadIdx.x >= o) ? s[threadIdx.x - o] : 0;
    __syncthreads();
    s[threadIdx.x] += t;
    __syncthreads();
  }
  if (i < N) off[i] = s[threadIdx.x] - v;
  if (threadIdx.x == 255) bsum[blockIdx.x] = s[255];
}

__global__ __launch_bounds__(256) void k_scan2(int* __restrict__ bsum) {
  __shared__ int s[256];
  int v = (threadIdx.x < NB_SCAN) ? bsum[threadIdx.x] : 0;
  s[threadIdx.x] = v;
  __syncthreads();
#pragma unroll
  for (int o = 1; o < 256; o <<= 1) {
    int t = (threadIdx.x >= o) ? s[threadIdx.x - o] : 0;
    __syncthreads();
    s[threadIdx.x] += t;
    __syncthreads();
  }
  if (threadIdx.x < NB_SCAN) bsum[threadIdx.x] = s[threadIdx.x] - v;
}

__global__ __launch_bounds__(256) void k_scan3(int* __restrict__ off,
                                               const int* __restrict__ bsum) {
  int i = blockIdx.x * 256 + threadIdx.x;
  if (i < N) off[i] += bsum[i >> 8];
  if (i == 0) off[N] = E;
}

// ---------------- bucket scatter: single flat pass, atomic-free ----------------
// ssrc[off[d] + rank] = src. Streamed dst32 + srk, cached off, scattered 4B write.
__global__ __launch_bounds__(256) void k_bucket(const int* __restrict__ dst32,
                                                const int2* __restrict__ srk,
                                                const int* __restrict__ off,
                                                int* __restrict__ ssrc) {
  int e = blockIdx.x * 256 + threadIdx.x;  // grid exact: 3125*256 = E
  int d = dst32[e];
  int2 sr = srk[e];
  ssrc[off[d] + sr.y] = sr.x;
}

// ---------------- gather-aggregate (f16): agg[n] = x[n] + sum_{j} x[src_j]
// 16 nodes/block x 16 lanes; lane owns 8 dims (16B); 8-way unrolled MLP.
__global__ __launch_bounds__(256) void k_gather_f16(const f16* __restrict__ x,
                                                    const int* __restrict__ off,
                                                    const int* __restrict__ ssrc,
                                                    f16* __restrict__ agg) {
  int n = blockIdx.x * 16 + (threadIdx.x >> 4);
  if (n >= N) return;
  const int d0 = (threadIdx.x & 15) << 3;
  f16x8 v = *(const f16x8*)(x + (size_t)n * D + d0);
  float acc[8];
#pragma unroll
  for (int j = 0; j < 8; ++j) acc[j] = (float)v[j];
  const int beg = off[n], end = off[n + 1];
  int p = beg;
  for (; p + 8 <= end; p += 8) {
    f16x8 u[8];
#pragma unroll
    for (int q = 0; q < 8; ++q) {
      int s = ssrc[p + q];
      u[q] = *(const f16x8*)(x + (size_t)s * D + d0);
    }
#pragma unroll
    for (int q = 0; q < 8; ++q)
#pragma unroll
      for (int j = 0; j < 8; ++j) acc[j] += (float)u[q][j];
  }
  if (p + 4 <= end) {
    f16x8 u[4];
#pragma unroll
    for (int q = 0; q < 4; ++q) {
      int s = ssrc[p + q];
      u[q] = *(const f16x8*)(x + (size_t)s * D + d0);
    }
#pragma unroll
    for (int q = 0; q < 4; ++q)
#pragma unroll
      for (int j = 0; j < 8; ++j) acc[j] += (float)u[q][j];
    p += 4;
  }
  for (; p < end; ++p) {
    int s = ssrc[p];
    f16x8 u = *(const f16x8*)(x + (size_t)s * D + d0);
#pragma unroll
    for (int j = 0; j < 8; ++j) acc[j] += (float)u[j];
  }
  f16x8 o;
#pragma unroll
  for (int j = 0; j < 8; ++j) o[j] = (f16)acc[j];
  *(f16x8*)(agg + (size_t)n * D + d0) = o;
}

// ---------------- fused double MFMA GEMM + bias + ReLU ----------------
// x' = relu(relu(A@W1+b1)@W2+b2). A f16 row-major; Wt* f16 [col][k].
// Block: 256 thr = 4 waves, 64 rows. h (64x128 f16) never leaves LDS.
__global__ __launch_bounds__(256) void k_gemm_fused(const f16* __restrict__ A,
                                                    const f16* __restrict__ Wt1,
                                                    const f16* __restrict__ Wt2,
                                                    const float* __restrict__ b1,
                                                    const float* __restrict__ b2,
                                                    f16* __restrict__ Ch,
                                                    float* __restrict__ Cf) {
  __shared__ f16 Ws[2][128 * WROW];
  {
    const f16x8* g1 = (const f16x8*)Wt1;
    const f16x8* g2 = (const f16x8*)Wt2;
    for (int i = threadIdx.x; i < 2048; i += 256) {
      int c = i >> 4;
      int k8 = (i & 15) << 3;
      *(f16x8*)&Ws[0][c * WROW + k8] = g1[i];
      *(f16x8*)&Ws[1][c * WROW + k8] = g2[i];
    }
  }
  __syncthreads();

  const int w = threadIdx.x >> 6;
  const int l = threadIdx.x & 63;
  const int l15 = l & 15;
  const int g = l >> 4;
  const int r0 = blockIdx.x * 64 + w * 16;

  // ---- phase A: h = relu(A @ W1 + b1) ----
  const int arow = min(r0 + l15, N - 1);
  const f16* Arow = A + (size_t)arow * D;
  f16x8 a[4];
#pragma unroll
  for (int t = 0; t < 4; ++t)
    a[t] = *(const f16x8*)(Arow + t * 32 + g * 8);

  float bc1[8], bc2[8];
#pragma unroll
  for (int c = 0; c < 8; ++c) {
    bc1[c] = b1[c * 16 + l15];
    bc2[c] = b2[c * 16 + l15];
  }

  f32x4 acc[8];
#pragma unroll
  for (int c = 0; c < 8; ++c) acc[c] = (f32x4){0.f, 0.f, 0.f, 0.f};
#pragma unroll
  for (int t = 0; t < 4; ++t) {
#pragma unroll
    for (int c = 0; c < 8; ++c) {
      f16x8 b = *(const f16x8*)&Ws[0][(c * 16 + l15) * WROW + t * 32 + g * 8];
      acc[c] = __builtin_amdgcn_mfma_f32_16x16x32_f16(a[t], b, acc[c], 0, 0, 0);
    }
  }

  __syncthreads();  // all waves done reading Ws[0]

  f16* hbuf = &Ws[0][0];
#pragma unroll
  for (int r = 0; r < 4; ++r) {
    int hr = w * 16 + g * 4 + r;
#pragma unroll
    for (int c = 0; c < 8; ++c) {
      float vv = fmaxf(acc[c][r] + bc1[c], 0.0f);
      hbuf[hr * WROW + c * 16 + l15] = (f16)vv;
    }
  }
  __syncthreads();

  // ---- phase B: x' = relu(h @ W2 + b2) ----
  f16x8 a2[4];
#pragma unroll
  for (int t = 0; t < 4; ++t)
    a2[t] = *(const f16x8*)&hbuf[(w * 16 + l15) * WROW + t * 32 + g * 8];

#pragma unroll
  for (int c = 0; c < 8; ++c) acc[c] = (f32x4){0.f, 0.f, 0.f, 0.f};
#pragma unroll
  for (int t = 0; t < 4; ++t) {
#pragma unroll
    for (int c = 0; c < 8; ++c) {
      f16x8 b = *(const f16x8*)&Ws[1][(c * 16 + l15) * WROW + t * 32 + g * 8];
      acc[c] = __builtin_amdgcn_mfma_f32_16x16x32_f16(a2[t], b, acc[c], 0, 0, 0);
    }
  }

#pragma unroll
  for (int r = 0; r < 4; ++r) {
    int rr = r0 + g * 4 + r;
    if (rr < N) {
#pragma unroll
      for (int c = 0; c < 8; ++c) {
        int col = c * 16 + l15;
        float vv = fmaxf(acc[c][r] + bc2[c], 0.0f);
        Ch[(size_t)rr * D + col] = (f16)vv;
        if (Cf) Cf[(size_t)rr * D + col] = vv;
      }
    }
  }
}

extern "C" void kernel_launch(void* const* d_in, const int* in_sizes, int n_in,
                              void* d_out, int out_size, void* d_ws, size_t ws_size,
                              hipStream_t stream) {
  const float* x0 = (const float*)d_in[0];
  const int* ei   = (const int*)d_in[1];
  const float* W1 = (const float*)d_in[2];
  const float* b1 = (const float*)d_in[3];
  const float* W2 = (const float*)d_in[4];
  const float* b2 = (const float*)d_in[5];
  float* out = (float*)d_out;

  // workspace layout (f16 arrays, then int2 (8B-aligned), then ints)
  f16* xh    = (f16*)d_ws;                          // N*D
  f16* aggh  = xh + (size_t)N * D;                  // N*D
  f16* Wt    = aggh + (size_t)N * D;                // 2*L*D*D
  int2* srk  = (int2*)(Wt + (size_t)2 * L * D * D); // E  (8B aligned: see note)
  int* dst32 = (int*)(srk + E);                     // E
  int* off   = dst32 + E;                           // N+1
  int* cnt   = off + (N + 1);                       // N
  int* bsum  = cnt + N;                             // 256
  int* ssrc  = bsum + 256;                          // E

  const dim3 blk(256);

  // ---- one-time prep ----
  hipMemsetAsync(cnt, 0, (size_t)N * sizeof(int), stream);
  k_init<<<384 + 3125 + 3125, blk, 0, stream>>>(x0, ei, W1, W2, Wt, xh, dst32,
                                                srk, cnt);
  k_scan1<<<NB_SCAN, blk, 0, stream>>>(cnt, off, bsum);
  k_scan2<<<1, blk, 0, stream>>>(bsum);
  k_scan3<<<NB_SCAN, blk, 0, stream>>>(off, bsum);
  k_bucket<<<E / 256, blk, 0, stream>>>(dst32, srk, off, ssrc);

  const int gemm_blocks = (N + 63) / 64;  // 782
  const int gather_blocks = N / 16;       // 3125

  for (int l = 0; l < L; ++l) {
    k_gather_f16<<<gather_blocks, blk, 0, stream>>>(xh, off, ssrc, aggh);
    k_gemm_fused<<<gemm_blocks, blk, 0, stream>>>(
        aggh, Wt + (size_t)l * D * D, Wt + (size_t)(L + l) * D * D,
        b1 + (size_t)l * D, b2 + (size_t)l * D, xh,
        (l == L - 1) ? out : nullptr);
  }
}